// Round 4
// baseline (225.267 us; speedup 1.0000x reference)
//
#include <hip/hip_runtime.h>
#include <hip/hip_bf16.h>

#define N_PTS 16384
#define PER   2048
#define M_CTR 4096
#define KNB   64
#define C_IN  128
#define HID   256
#define C_OUT 256

typedef unsigned short u16;
typedef unsigned int u32;
typedef __attribute__((ext_vector_type(8))) short s8v;    // 8 bf16 (4 VGPRs)
typedef __attribute__((ext_vector_type(4))) float f4v;
typedef __attribute__((ext_vector_type(4))) unsigned int u4v;

static __device__ __forceinline__ u16 f2bf(float f) {
    union { float f; unsigned int i; } v; v.f = f;
    unsigned int r = v.i + 0x7FFFu + ((v.i >> 16) & 1u);
    return (u16)(r >> 16);
}

// ---------------------------------------------------------------- ballq (+prep folded into first 256 blocks)
// d2 replicates the reference float32 gemm-trick bit-for-bit (see r2 notes).
__global__ __launch_bounds__(256) void ballq_kernel(
        const float* __restrict__ pos, int* __restrict__ nbr, int* __restrict__ cnt,
        const float* __restrict__ W1, const float* __restrict__ W2,
        u16* __restrict__ W1aT, u16* __restrict__ W1bT, u16* __restrict__ W2T) {
    __shared__ float cd2[1024];
    __shared__ int   cidx[1024];
    __shared__ int   s_n;
    int m = blockIdx.x, tid = threadIdx.x;

    if (m < 256) {
        int gid = m * 256 + tid;
        int cc = gid >> 8, k = gid & 255;
        W2T[gid] = f2bf(W2[k * 256 + cc]);               // W2T[c][k]
        if (gid < 32768) {
            int c1 = gid >> 7, k1 = gid & 127;
            W1aT[gid] = f2bf(W1[k1 * 256 + c1]);         // rows 0:128
            W1bT[gid] = f2bf(W1[(k1 + 128) * 256 + c1]); // rows 128:256
        }
    }

    int c = m * 4;
    int base = (m >> 9) << 11;                            // cloud start
    if (tid == 0) s_n = 0;
    __syncthreads();
    float cx = pos[c * 3 + 0], cy = pos[c * 3 + 1], cz = pos[c * 3 + 2];
    float A = __fadd_rn(__fadd_rn(__fmul_rn(cx, cx), __fmul_rn(cy, cy)), __fmul_rn(cz, cz));
    float c2x = __fmul_rn(2.0f, cx);
    float c2y = __fmul_rn(2.0f, cy);
    float c2z = __fmul_rn(2.0f, cz);
    for (int s = 0; s < 8; ++s) {
        int j = base + tid + (s << 8);
        float px = pos[j * 3 + 0], py = pos[j * 3 + 1], pz = pos[j * 3 + 2];
        float B = __fadd_rn(__fadd_rn(__fmul_rn(px, px), __fmul_rn(py, py)), __fmul_rn(pz, pz));
        float C = __fmaf_rn(c2z, pz, __fmaf_rn(c2y, py, __fmul_rn(c2x, px)));
        float d2 = __fsub_rn(__fadd_rn(A, B), C);
        if (d2 <= 0.0625f) {
            int a = atomicAdd(&s_n, 1);
            if (a < 1024) { cd2[a] = d2; cidx[a] = j; }
        }
    }
    __syncthreads();
    int V = s_n < 1024 ? s_n : 1024;
    if (V <= KNB) {
        if (tid < KNB) nbr[m * KNB + tid] = (tid < V) ? cidx[tid] : c;
        if (tid == 0) cnt[m] = V;
    } else {
        for (int e = tid; e < V; e += 256) {
            float de = cd2[e]; int ie = cidx[e];
            int rank = 0;
            for (int q = 0; q < V; ++q) {
                float dq = cd2[q];
                rank += (dq < de) || (dq == de && cidx[q] < ie);
            }
            if (rank < KNB) nbr[m * KNB + rank] = cidx[e];
        }
        if (tid == 0) cnt[m] = KNB;
    }
}

// ---------------------------------------------------------------- fused u = x@W1a (blocks 0..255) / v = x[4m]@W1b + b1 (blocks 256..319)
__global__ __launch_bounds__(256) void gemm_xw_kernel(
        const float* __restrict__ x, const u16* __restrict__ W1aT, const u16* __restrict__ W1bT,
        const float* __restrict__ b1, u16* __restrict__ u_out, float* __restrict__ v_out) {
    __shared__ u16 x_lds[64 * 136];
    int blk = blockIdx.x, tid = threadIdx.x;
    int mode = blk >= 256 ? 1 : 0;
    int bb = mode ? blk - 256 : blk;
    const u16* WT = mode ? W1bT : W1aT;
    {
        int r = tid >> 2, q = tid & 3;
        int xrow = bb * 64 + r;
        if (mode) xrow *= 4;
        const float* xp = x + xrow * C_IN + q * 32;
        u16* dst = x_lds + r * 136 + q * 32;
        for (int i = 0; i < 8; ++i) {
            f4v f = *(const f4v*)(xp + i * 4);
            dst[i * 4 + 0] = f2bf(f[0]);
            dst[i * 4 + 1] = f2bf(f[1]);
            dst[i * 4 + 2] = f2bf(f[2]);
            dst[i * 4 + 3] = f2bf(f[3]);
        }
    }
    __syncthreads();
    int lane = tid & 63, w = tid >> 6;
    int quad = lane >> 4, l16 = lane & 15;
    int cb = w * 64;
    f4v acc[4][4] = {};
    for (int k0 = 0; k0 < 128; k0 += 32) {
        s8v a[4], b[4];
        for (int rt = 0; rt < 4; ++rt)
            a[rt] = *(const s8v*)&x_lds[(rt * 16 + l16) * 136 + k0 + quad * 8];
        for (int ct = 0; ct < 4; ++ct)
            b[ct] = *(const s8v*)(WT + (cb + ct * 16 + l16) * 128 + k0 + quad * 8);
        for (int rt = 0; rt < 4; ++rt)
            for (int ct = 0; ct < 4; ++ct)
                acc[rt][ct] = __builtin_amdgcn_mfma_f32_16x16x32_bf16(a[rt], b[ct], acc[rt][ct], 0, 0, 0);
    }
    for (int rt = 0; rt < 4; ++rt)
        for (int ct = 0; ct < 4; ++ct)
            for (int g = 0; g < 4; ++g) {
                int row = rt * 16 + quad * 4 + g;
                int col = cb + ct * 16 + l16;
                float val = acc[rt][ct][g];
                int orow = bb * 64 + row;
                if (mode == 0) u_out[orow * 256 + col] = f2bf(val);
                else           v_out[orow * 256 + col] = val + b1[col];
            }
}

// ---------------------------------------------------------------- fused edge conv
// 512 threads = 8 waves; 4 center-pairs per block; M-tile 128 (2 centers share B).
// Wave w: rows (w>>2)*64 (one center), cols (w&3)*64. Waves w, w+4 read the same
// W2T slice back-to-back -> L1 reuse halves L2 B-traffic. Pair metadata is
// double-buffered and prefetched during the previous pair's phase 1.
__global__ __launch_bounds__(512, 4) void edge_kernel(
        const u16* __restrict__ u, const float* __restrict__ v,
        const u16* __restrict__ W2T, const float* __restrict__ W1,
        const float* __restrict__ b2, const float* __restrict__ pos,
        const float* __restrict__ lframes, const int* __restrict__ batch,
        const int* __restrict__ nbrg, const int* __restrict__ cnt,
        float* __restrict__ out0, float* __restrict__ out_pos,
        float* __restrict__ out_batch, float* __restrict__ out_lf) {
    __shared__ u16   h_lds[128 * 264];                   // 67584 B
    __shared__ float v_lds[2][2][256];                   // 4096 B  [buf][g][col]
    __shared__ float w1c_lds[768];                       // 3072 B
    __shared__ float relc_lds[2][2][64][3];              // 3072 B
    __shared__ u16   nbr_lds[2][2][64];                  // 512 B
    __shared__ int   cnt_lds[2][2];

    int blk = blockIdx.x, tid = threadIdx.x;
    int m0 = ((blk & 7) << 9) | ((blk >> 3) << 3);       // 8 consecutive centers, cloud == XCD

    // ---- prologue
    for (int i = tid; i < 768; i += 512) w1c_lds[i] = W1[65536 + i];
    if (tid < 128) {                                     // meta for pair 0
        int g = tid >> 6, t = tid & 63;
        int mm = m0 + g, cc = mm * 4;
        int j = nbrg[mm * KNB + t];
        nbr_lds[0][g][t] = (u16)j;
        float rx = pos[j * 3 + 0] - pos[cc * 3 + 0];
        float ry = pos[j * 3 + 1] - pos[cc * 3 + 1];
        float rz = pos[j * 3 + 2] - pos[cc * 3 + 2];
        const float* lf = lframes + cc * 9;
        relc_lds[0][g][t][0] = lf[0] * rx + lf[1] * ry + lf[2] * rz;
        relc_lds[0][g][t][1] = lf[3] * rx + lf[4] * ry + lf[5] * rz;
        relc_lds[0][g][t][2] = lf[6] * rx + lf[7] * ry + lf[8] * rz;
    }
    v_lds[0][tid >> 8][tid & 255] = v[(m0 + (tid >> 8)) * 256 + (tid & 255)];
    if (tid == 508) cnt_lds[0][0] = cnt[m0];
    if (tid == 509) cnt_lds[0][1] = cnt[m0 + 1];
    if (tid >= 256 && tid < 384) {                       // aux outputs for all 8 centers
        int g = (tid - 256) >> 4, t = tid & 15;
        int mm = m0 + g, cc = mm * 4;
        if (t < 3)            out_pos[mm * 3 + t] = pos[cc * 3 + t];
        else if (t == 3)      out_batch[mm] = (float)batch[cc];
        else if (t < 13)      out_lf[mm * 9 + (t - 4)] = lframes[cc * 9 + (t - 4)];
    }
    __syncthreads();

    int co = (tid & 31) * 8;                             // 8-col slice
    int rs = tid >> 5;                                   // 0..15, rows rs+16*ii
    int lane = tid & 63, w = tid >> 6;
    int quad = lane >> 4, l16 = lane & 15;
    int cb = (w & 3) * 64;
    int rbase = (w >> 2) * 64;
    float b2c[4];
    #pragma unroll
    for (int ct = 0; ct < 4; ++ct) b2c[ct] = b2[cb + ct * 16 + l16];

    for (int p = 0; p < 4; ++p) {
        int pb = p & 1;
        // ---- phase 1: h[128][256] = relu(u[nbr] + v + relc @ W1c)
        float wa[8], wb[8], wc[8], vv[2][8];
        #pragma unroll
        for (int e = 0; e < 8; ++e) {
            wa[e] = w1c_lds[co + e];
            wb[e] = w1c_lds[256 + co + e];
            wc[e] = w1c_lds[512 + co + e];
            vv[0][e] = v_lds[pb][0][co + e];
            vv[1][e] = v_lds[pb][1][co + e];
        }
        #pragma unroll
        for (int ii = 0; ii < 8; ++ii) {
            int row = rs + ii * 16;
            int g = ii >> 2;                             // center within pair
            int rl = row & 63;
            int j = (int)nbr_lds[pb][g][rl];
            u4v uu = *(const u4v*)(u + j * 256 + co);
            float r0 = relc_lds[pb][g][rl][0];
            float r1 = relc_lds[pb][g][rl][1];
            float r2 = relc_lds[pb][g][rl][2];
            float p8[8];
            #pragma unroll
            for (int e = 0; e < 8; ++e) {
                u32 bits = (e & 1) ? (uu[e >> 1] & 0xFFFF0000u) : (uu[e >> 1] << 16);
                float pre = fmaf(r0, wa[e], fmaf(r1, wb[e], fmaf(r2, wc[e],
                              vv[g][e] + __uint_as_float(bits))));
                p8[e] = fmaxf(pre, 0.0f);
            }
            u4v pk;
            #pragma unroll
            for (int d = 0; d < 4; ++d)
                pk[d] = __builtin_amdgcn_perm(__float_as_uint(p8[2 * d + 1]),
                                              __float_as_uint(p8[2 * d]), 0x07060302u);
            *(u4v*)&h_lds[row * 264 + co] = pk;
        }
        // ---- prefetch next pair's metadata into the other buffer
        if (p < 3) {
            int nb = (p + 1) & 1;
            int mbase = m0 + (p + 1) * 2;
            if (tid < 128) {
                int g = tid >> 6, t = tid & 63;
                int mm = mbase + g, cc = mm * 4;
                int j = nbrg[mm * KNB + t];
                nbr_lds[nb][g][t] = (u16)j;
                float rx = pos[j * 3 + 0] - pos[cc * 3 + 0];
                float ry = pos[j * 3 + 1] - pos[cc * 3 + 1];
                float rz = pos[j * 3 + 2] - pos[cc * 3 + 2];
                const float* lf = lframes + cc * 9;
                relc_lds[nb][g][t][0] = lf[0] * rx + lf[1] * ry + lf[2] * rz;
                relc_lds[nb][g][t][1] = lf[3] * rx + lf[4] * ry + lf[5] * rz;
                relc_lds[nb][g][t][2] = lf[6] * rx + lf[7] * ry + lf[8] * rz;
            }
            v_lds[nb][tid >> 8][tid & 255] = v[(mbase + (tid >> 8)) * 256 + (tid & 255)];
            if (tid == 508) cnt_lds[nb][0] = cnt[mbase];
            if (tid == 509) cnt_lds[nb][1] = cnt[mbase + 1];
        }
        __syncthreads();                                  // h + next-meta ready

        // ---- phase 2: [128x256] @ [256x256]
        f4v acc[4][4] = {};
        for (int k0 = 0; k0 < 256; k0 += 32) {
            s8v a[4], b[4];
            #pragma unroll
            for (int rt = 0; rt < 4; ++rt)
                a[rt] = *(const s8v*)&h_lds[(rbase + rt * 16 + l16) * 264 + k0 + quad * 8];
            #pragma unroll
            for (int ct = 0; ct < 4; ++ct)
                b[ct] = *(const s8v*)(W2T + (cb + ct * 16 + l16) * 256 + k0 + quad * 8);
            #pragma unroll
            for (int rt = 0; rt < 4; ++rt)
                #pragma unroll
                for (int ct = 0; ct < 4; ++ct)
                    acc[rt][ct] = __builtin_amdgcn_mfma_f32_16x16x32_bf16(a[rt], b[ct], acc[rt][ct], 0, 0, 0);
        }
        // ---- epilogue: masked max over this wave's center, + b2
        int cv = cnt_lds[pb][w >> 2];
        int mout = m0 + p * 2 + (w >> 2);
        #pragma unroll
        for (int ct = 0; ct < 4; ++ct) {
            float mx = -__builtin_inff();
            #pragma unroll
            for (int rt = 0; rt < 4; ++rt)
                #pragma unroll
                for (int g = 0; g < 4; ++g) {
                    int row = rt * 16 + quad * 4 + g;    // row within center
                    float val = acc[rt][ct][g];
                    if (row < cv) mx = fmaxf(mx, val);
                }
            mx = fmaxf(mx, __shfl_xor(mx, 16, 64));
            mx = fmaxf(mx, __shfl_xor(mx, 32, 64));
            if (lane < 16)
                out0[mout * 256 + cb + ct * 16 + l16] = mx + b2c[ct];
        }
        __syncthreads();                                  // h consumed
    }
}

extern "C" void kernel_launch(void* const* d_in, const int* in_sizes, int n_in,
                              void* d_out, int out_size, void* d_ws, size_t ws_size,
                              hipStream_t stream) {
    const float* x       = (const float*)d_in[0];
    const float* pos     = (const float*)d_in[1];
    const int*   batch   = (const int*)d_in[2];
    const float* lframes = (const float*)d_in[3];
    const float* W1      = (const float*)d_in[4];
    const float* b1      = (const float*)d_in[5];
    const float* W2      = (const float*)d_in[6];
    const float* b2      = (const float*)d_in[7];

    float* out       = (float*)d_out;
    float* out_pos   = out + M_CTR * 256;
    float* out_batch = out_pos + M_CTR * 3;
    float* out_lf    = out_batch + M_CTR;

    char* ws = (char*)d_ws;
    u16*   u_ws = (u16*)(ws);                    // N*256 bf16   = 8 MB
    float* v_ws = (float*)(ws + 8388608);        // M*256 f32    = 4 MB
    u16*   W1aT = (u16*)(ws + 12582912);
    u16*   W1bT = (u16*)(ws + 12648448);
    u16*   W2T  = (u16*)(ws + 12713984);
    int*   nbr  = (int*)(ws + 12845056);
    int*   cntp = (int*)(ws + 13893632);

    hipLaunchKernelGGL(ballq_kernel, dim3(M_CTR), dim3(256), 0, stream,
                       pos, nbr, cntp, W1, W2, W1aT, W1bT, W2T);
    hipLaunchKernelGGL(gemm_xw_kernel, dim3(320), dim3(256), 0, stream,
                       x, W1aT, W1bT, b1, u_ws, v_ws);
    hipLaunchKernelGGL(edge_kernel, dim3(512), dim3(512), 0, stream,
                       u_ws, v_ws, W2T, W1, b2, pos, lframes, batch, nbr, cntp,
                       out, out_pos, out_batch, out_lf);
}

// Round 5
// 176.885 us; speedup vs baseline: 1.2735x; 1.2735x over previous
//
#include <hip/hip_runtime.h>
#include <hip/hip_bf16.h>

#define N_PTS 16384
#define PER   2048
#define M_CTR 4096
#define KNB   64
#define C_IN  128
#define HID   256
#define C_OUT 256

typedef unsigned short u16;
typedef unsigned int u32;
typedef __attribute__((ext_vector_type(8))) short s8v;    // 8 bf16 (4 VGPRs)
typedef __attribute__((ext_vector_type(4))) float f4v;
typedef __attribute__((ext_vector_type(4))) unsigned int u4v;

static __device__ __forceinline__ u16 f2bf(float f) {
    union { float f; unsigned int i; } v; v.f = f;
    unsigned int r = v.i + 0x7FFFu + ((v.i >> 16) & 1u);
    return (u16)(r >> 16);
}

// ---------------------------------------------------------------- ballq (+prep folded into first 256 blocks)
// d2 replicates the reference float32 gemm-trick bit-for-bit (see r2 notes).
__global__ __launch_bounds__(256) void ballq_kernel(
        const float* __restrict__ pos, int* __restrict__ nbr, int* __restrict__ cnt,
        const float* __restrict__ W1, const float* __restrict__ W2,
        u16* __restrict__ W1aT, u16* __restrict__ W1bT, u16* __restrict__ W2T) {
    __shared__ float cd2[1024];
    __shared__ int   cidx[1024];
    __shared__ int   s_n;
    int m = blockIdx.x, tid = threadIdx.x;

    if (m < 256) {
        int gid = m * 256 + tid;
        int cc = gid >> 8, k = gid & 255;
        W2T[gid] = f2bf(W2[k * 256 + cc]);               // W2T[c][k]
        if (gid < 32768) {
            int c1 = gid >> 7, k1 = gid & 127;
            W1aT[gid] = f2bf(W1[k1 * 256 + c1]);         // rows 0:128
            W1bT[gid] = f2bf(W1[(k1 + 128) * 256 + c1]); // rows 128:256
        }
    }

    int c = m * 4;
    int base = (m >> 9) << 11;                            // cloud start
    if (tid == 0) s_n = 0;
    __syncthreads();
    float cx = pos[c * 3 + 0], cy = pos[c * 3 + 1], cz = pos[c * 3 + 2];
    float A = __fadd_rn(__fadd_rn(__fmul_rn(cx, cx), __fmul_rn(cy, cy)), __fmul_rn(cz, cz));
    float c2x = __fmul_rn(2.0f, cx);
    float c2y = __fmul_rn(2.0f, cy);
    float c2z = __fmul_rn(2.0f, cz);
    for (int s = 0; s < 8; ++s) {
        int j = base + tid + (s << 8);
        float px = pos[j * 3 + 0], py = pos[j * 3 + 1], pz = pos[j * 3 + 2];
        float B = __fadd_rn(__fadd_rn(__fmul_rn(px, px), __fmul_rn(py, py)), __fmul_rn(pz, pz));
        float C = __fmaf_rn(c2z, pz, __fmaf_rn(c2y, py, __fmul_rn(c2x, px)));
        float d2 = __fsub_rn(__fadd_rn(A, B), C);
        if (d2 <= 0.0625f) {
            int a = atomicAdd(&s_n, 1);
            if (a < 1024) { cd2[a] = d2; cidx[a] = j; }
        }
    }
    __syncthreads();
    int V = s_n < 1024 ? s_n : 1024;
    if (V <= KNB) {
        if (tid < KNB) nbr[m * KNB + tid] = (tid < V) ? cidx[tid] : c;
        if (tid == 0) cnt[m] = V;
    } else {
        for (int e = tid; e < V; e += 256) {
            float de = cd2[e]; int ie = cidx[e];
            int rank = 0;
            for (int q = 0; q < V; ++q) {
                float dq = cd2[q];
                rank += (dq < de) || (dq == de && cidx[q] < ie);
            }
            if (rank < KNB) nbr[m * KNB + rank] = cidx[e];
        }
        if (tid == 0) cnt[m] = KNB;
    }
}

// ---------------------------------------------------------------- fused u = x@W1a (blocks 0..255) / v = x[4m]@W1b + b1 (blocks 256..319)
__global__ __launch_bounds__(256) void gemm_xw_kernel(
        const float* __restrict__ x, const u16* __restrict__ W1aT, const u16* __restrict__ W1bT,
        const float* __restrict__ b1, u16* __restrict__ u_out, float* __restrict__ v_out) {
    __shared__ u16 x_lds[64 * 136];
    int blk = blockIdx.x, tid = threadIdx.x;
    int mode = blk >= 256 ? 1 : 0;
    int bb = mode ? blk - 256 : blk;
    const u16* WT = mode ? W1bT : W1aT;
    {
        int r = tid >> 2, q = tid & 3;
        int xrow = bb * 64 + r;
        if (mode) xrow *= 4;
        const float* xp = x + xrow * C_IN + q * 32;
        u16* dst = x_lds + r * 136 + q * 32;
        for (int i = 0; i < 8; ++i) {
            f4v f = *(const f4v*)(xp + i * 4);
            dst[i * 4 + 0] = f2bf(f[0]);
            dst[i * 4 + 1] = f2bf(f[1]);
            dst[i * 4 + 2] = f2bf(f[2]);
            dst[i * 4 + 3] = f2bf(f[3]);
        }
    }
    __syncthreads();
    int lane = tid & 63, w = tid >> 6;
    int quad = lane >> 4, l16 = lane & 15;
    int cb = w * 64;
    f4v acc[4][4] = {};
    for (int k0 = 0; k0 < 128; k0 += 32) {
        s8v a[4], b[4];
        for (int rt = 0; rt < 4; ++rt)
            a[rt] = *(const s8v*)&x_lds[(rt * 16 + l16) * 136 + k0 + quad * 8];
        for (int ct = 0; ct < 4; ++ct)
            b[ct] = *(const s8v*)(WT + (cb + ct * 16 + l16) * 128 + k0 + quad * 8);
        for (int rt = 0; rt < 4; ++rt)
            for (int ct = 0; ct < 4; ++ct)
                acc[rt][ct] = __builtin_amdgcn_mfma_f32_16x16x32_bf16(a[rt], b[ct], acc[rt][ct], 0, 0, 0);
    }
    for (int rt = 0; rt < 4; ++rt)
        for (int ct = 0; ct < 4; ++ct)
            for (int g = 0; g < 4; ++g) {
                int row = rt * 16 + quad * 4 + g;
                int col = cb + ct * 16 + l16;
                float val = acc[rt][ct][g];
                int orow = bb * 64 + row;
                if (mode == 0) u_out[orow * 256 + col] = f2bf(val);
                else           v_out[orow * 256 + col] = val + b1[col];
            }
}

// ---------------------------------------------------------------- fused edge conv
// 512 threads = 8 waves; M-tile 128 (2 centers); 4 pairs per block; grid 512.
// h double-buffered in LDS (147 KB total) -> ONE barrier per pair: phase-2(p)
// [MFMA] of one wave overlaps phase-1(p+1) [VALU] of its SIMD-mate (m114).
// __launch_bounds__(512,2): 256-reg cap, no spills (r4 lesson); 1 block/CU
// (LDS-bound) is intentional. cnt flows through a per-wave register chain
// so no LDS meta is read after the barrier-free phase-2.
__global__ __launch_bounds__(512, 2) void edge_kernel(
        const u16* __restrict__ u, const float* __restrict__ v,
        const u16* __restrict__ W2T, const float* __restrict__ W1,
        const float* __restrict__ b2, const float* __restrict__ pos,
        const float* __restrict__ lframes, const int* __restrict__ batch,
        const int* __restrict__ nbrg, const int* __restrict__ cnt,
        float* __restrict__ out0, float* __restrict__ out_pos,
        float* __restrict__ out_batch, float* __restrict__ out_lf) {
    __shared__ u16   h_lds[2][128 * 264];                // 135168 B
    __shared__ float v_lds[2][2][256];                   // 4096 B
    __shared__ float w1c_lds[768];                       // 3072 B
    __shared__ f4v   relc_lds[2][2][64];                 // 4096 B
    __shared__ u16   nbr_lds[2][2][64];                  // 512 B

    int blk = blockIdx.x, tid = threadIdx.x;
    int m0 = ((blk & 7) << 9) | ((blk >> 3) << 3);       // 8 consecutive centers, cloud == XCD

    // ---- prologue
    for (int i = tid; i < 768; i += 512) w1c_lds[i] = W1[65536 + i];
    if (tid < 128) {                                     // meta for pair 0
        int g = tid >> 6, t = tid & 63;
        int mm = m0 + g, cc = mm * 4;
        int j = nbrg[mm * KNB + t];
        nbr_lds[0][g][t] = (u16)j;
        float rx = pos[j * 3 + 0] - pos[cc * 3 + 0];
        float ry = pos[j * 3 + 1] - pos[cc * 3 + 1];
        float rz = pos[j * 3 + 2] - pos[cc * 3 + 2];
        const float* lf = lframes + cc * 9;
        f4v r;
        r[0] = lf[0] * rx + lf[1] * ry + lf[2] * rz;
        r[1] = lf[3] * rx + lf[4] * ry + lf[5] * rz;
        r[2] = lf[6] * rx + lf[7] * ry + lf[8] * rz;
        r[3] = 0.0f;
        relc_lds[0][g][t] = r;
    }
    v_lds[0][tid >> 8][tid & 255] = v[(m0 + (tid >> 8)) * 256 + (tid & 255)];
    if (tid >= 256 && tid < 384) {                       // aux outputs, all 8 centers
        int g = (tid - 256) >> 4, t = tid & 15;
        int mm = m0 + g, cc = mm * 4;
        if (t < 3)            out_pos[mm * 3 + t] = pos[cc * 3 + t];
        else if (t == 3)      out_batch[mm] = (float)batch[cc];
        else if (t < 13)      out_lf[mm * 9 + (t - 4)] = lframes[cc * 9 + (t - 4)];
    }

    int co = (tid & 31) * 8;                             // 8-col slice
    int rs = tid >> 5;                                   // 0..15
    int lane = tid & 63, w = tid >> 6;
    int quad = lane >> 4, l16 = lane & 15;
    int cb = (w & 3) * 64;
    int rbase = (w >> 2) * 64;
    int gsel = w >> 2;                                   // wave's center within pair
    int cv_cur = cnt[m0 + gsel];                         // pair-0 count (uniform/wave)
    __syncthreads();                                     // meta[0] + w1c ready

    // w1c columns cached once (24 regs, live whole kernel)
    float wa[8], wb[8], wc[8];
    #pragma unroll
    for (int e = 0; e < 8; ++e) {
        wa[e] = w1c_lds[co + e];
        wb[e] = w1c_lds[256 + co + e];
        wc[e] = w1c_lds[512 + co + e];
    }

    int cv_next = 0;
    for (int p = 0; p < 4; ++p) {
        int pb = p & 1;
        // ---- phase 1: h[pb][128][256] = relu(u[nbr] + v + relc @ W1c)
        #pragma unroll
        for (int g = 0; g < 2; ++g) {
            f4v vq0 = *(const f4v*)&v_lds[pb][g][co];
            f4v vq1 = *(const f4v*)&v_lds[pb][g][co + 4];
            #pragma unroll
            for (int i2 = 0; i2 < 4; ++i2) {
                int rl = rs + i2 * 16;                   // row within center
                int row = g * 64 + rl;
                int j = (int)nbr_lds[pb][g][rl];
                u4v uu = *(const u4v*)(u + j * 256 + co);
                f4v r = relc_lds[pb][g][rl];
                float p8[8];
                #pragma unroll
                for (int e = 0; e < 8; ++e) {
                    u32 bits = (e & 1) ? (uu[e >> 1] & 0xFFFF0000u) : (uu[e >> 1] << 16);
                    float va = (e < 4) ? vq0[e] : vq1[e - 4];
                    float pre = fmaf(r[0], wa[e], fmaf(r[1], wb[e], fmaf(r[2], wc[e],
                                  va + __uint_as_float(bits))));
                    p8[e] = fmaxf(pre, 0.0f);
                }
                u4v pk;
                #pragma unroll
                for (int d = 0; d < 4; ++d)
                    pk[d] = __builtin_amdgcn_perm(__float_as_uint(p8[2 * d + 1]),
                                                  __float_as_uint(p8[2 * d]), 0x07060302u);
                *(u4v*)&h_lds[pb][row * 264 + co] = pk;
            }
        }
        // ---- prefetch next pair's metadata into the other buffer
        if (p < 3) {
            int nb = pb ^ 1;
            int mbase = m0 + (p + 1) * 2;
            cv_next = cnt[mbase + gsel];
            if (tid < 128) {
                int g = tid >> 6, t = tid & 63;
                int mm = mbase + g, cc = mm * 4;
                int j = nbrg[mm * KNB + t];
                nbr_lds[nb][g][t] = (u16)j;
                float rx = pos[j * 3 + 0] - pos[cc * 3 + 0];
                float ry = pos[j * 3 + 1] - pos[cc * 3 + 1];
                float rz = pos[j * 3 + 2] - pos[cc * 3 + 2];
                const float* lf = lframes + cc * 9;
                f4v r;
                r[0] = lf[0] * rx + lf[1] * ry + lf[2] * rz;
                r[1] = lf[3] * rx + lf[4] * ry + lf[5] * rz;
                r[2] = lf[6] * rx + lf[7] * ry + lf[8] * rz;
                r[3] = 0.0f;
                relc_lds[nb][g][t] = r;
            }
            v_lds[nb][tid >> 8][tid & 255] = v[(mbase + (tid >> 8)) * 256 + (tid & 255)];
        }
        __syncthreads();                                 // h[pb] + meta[nb] ready

        // ---- phase 2: [128x256] @ [256x256] (no trailing barrier)
        f4v acc[4][4] = {};
        for (int k0 = 0; k0 < 256; k0 += 32) {
            s8v a[4], b[4];
            #pragma unroll
            for (int rt = 0; rt < 4; ++rt)
                a[rt] = *(const s8v*)&h_lds[pb][(rbase + rt * 16 + l16) * 264 + k0 + quad * 8];
            #pragma unroll
            for (int ct = 0; ct < 4; ++ct)
                b[ct] = *(const s8v*)(W2T + (cb + ct * 16 + l16) * 256 + k0 + quad * 8);
            #pragma unroll
            for (int rt = 0; rt < 4; ++rt)
                #pragma unroll
                for (int ct = 0; ct < 4; ++ct)
                    acc[rt][ct] = __builtin_amdgcn_mfma_f32_16x16x32_bf16(a[rt], b[ct], acc[rt][ct], 0, 0, 0);
        }
        // ---- epilogue: masked max over this wave's center, + b2
        int mout = m0 + p * 2 + gsel;
        #pragma unroll
        for (int ct = 0; ct < 4; ++ct) {
            float mx = -__builtin_inff();
            #pragma unroll
            for (int rt = 0; rt < 4; ++rt)
                #pragma unroll
                for (int g = 0; g < 4; ++g) {
                    int row = rt * 16 + quad * 4 + g;
                    float val = acc[rt][ct][g];
                    if (row < cv_cur) mx = fmaxf(mx, val);
                }
            mx = fmaxf(mx, __shfl_xor(mx, 16, 64));
            mx = fmaxf(mx, __shfl_xor(mx, 32, 64));
            if (lane < 16)
                out0[mout * 256 + cb + ct * 16 + l16] = mx + b2[cb + ct * 16 + l16];
        }
        cv_cur = cv_next;
    }
}

extern "C" void kernel_launch(void* const* d_in, const int* in_sizes, int n_in,
                              void* d_out, int out_size, void* d_ws, size_t ws_size,
                              hipStream_t stream) {
    const float* x       = (const float*)d_in[0];
    const float* pos     = (const float*)d_in[1];
    const int*   batch   = (const int*)d_in[2];
    const float* lframes = (const float*)d_in[3];
    const float* W1      = (const float*)d_in[4];
    const float* b1      = (const float*)d_in[5];
    const float* W2      = (const float*)d_in[6];
    const float* b2      = (const float*)d_in[7];

    float* out       = (float*)d_out;
    float* out_pos   = out + M_CTR * 256;
    float* out_batch = out_pos + M_CTR * 3;
    float* out_lf    = out_batch + M_CTR;

    char* ws = (char*)d_ws;
    u16*   u_ws = (u16*)(ws);                    // N*256 bf16   = 8 MB
    float* v_ws = (float*)(ws + 8388608);        // M*256 f32    = 4 MB
    u16*   W1aT = (u16*)(ws + 12582912);
    u16*   W1bT = (u16*)(ws + 12648448);
    u16*   W2T  = (u16*)(ws + 12713984);
    int*   nbr  = (int*)(ws + 12845056);
    int*   cntp = (int*)(ws + 13893632);

    hipLaunchKernelGGL(ballq_kernel, dim3(M_CTR), dim3(256), 0, stream,
                       pos, nbr, cntp, W1, W2, W1aT, W1bT, W2T);
    hipLaunchKernelGGL(gemm_xw_kernel, dim3(320), dim3(256), 0, stream,
                       x, W1aT, W1bT, b1, u_ws, v_ws);
    hipLaunchKernelGGL(edge_kernel, dim3(512), dim3(512), 0, stream,
                       u_ws, v_ws, W2T, W1, b2, pos, lframes, batch, nbr, cntp,
                       out, out_pos, out_batch, out_lf);
}

// Round 6
// 172.141 us; speedup vs baseline: 1.3086x; 1.0276x over previous
//
#include <hip/hip_runtime.h>
#include <hip/hip_bf16.h>

#define N_PTS 16384
#define PER   2048
#define M_CTR 4096
#define KNB   64
#define C_IN  128
#define HID   256
#define C_OUT 256

typedef unsigned short u16;
typedef unsigned int u32;
typedef __attribute__((ext_vector_type(8))) short s8v;    // 8 bf16 (4 VGPRs)
typedef __attribute__((ext_vector_type(4))) float f4v;
typedef __attribute__((ext_vector_type(4))) unsigned int u4v;

static __device__ __forceinline__ u16 f2bf(float f) {
    union { float f; unsigned int i; } v; v.f = f;
    unsigned int r = v.i + 0x7FFFu + ((v.i >> 16) & 1u);
    return (u16)(r >> 16);
}

// ---------------------------------------------------------------- ballq (+prep folded into first 256 blocks)
// d2 replicates the reference float32 gemm-trick bit-for-bit (see r2 notes).
// Candidate compaction via wave ballot: one LDS atomic per wave per iter.
__global__ __launch_bounds__(256) void ballq_kernel(
        const float* __restrict__ pos, int* __restrict__ nbr, int* __restrict__ cnt,
        const float* __restrict__ W1, const float* __restrict__ W2,
        u16* __restrict__ W1aT, u16* __restrict__ W1bT, u16* __restrict__ W2T) {
    __shared__ float cd2[1024];
    __shared__ int   cidx[1024];
    __shared__ int   s_n;
    int m = blockIdx.x, tid = threadIdx.x;

    if (m < 256) {
        int gid = m * 256 + tid;
        int cc = gid >> 8, k = gid & 255;
        W2T[gid] = f2bf(W2[k * 256 + cc]);               // W2T[c][k]
        if (gid < 32768) {
            int c1 = gid >> 7, k1 = gid & 127;
            W1aT[gid] = f2bf(W1[k1 * 256 + c1]);         // rows 0:128
            W1bT[gid] = f2bf(W1[(k1 + 128) * 256 + c1]); // rows 128:256
        }
    }

    int c = m * 4;
    int base = (m >> 9) << 11;                            // cloud start
    int ln = tid & 63;
    if (tid == 0) s_n = 0;
    __syncthreads();
    float cx = pos[c * 3 + 0], cy = pos[c * 3 + 1], cz = pos[c * 3 + 2];
    float A = __fadd_rn(__fadd_rn(__fmul_rn(cx, cx), __fmul_rn(cy, cy)), __fmul_rn(cz, cz));
    float c2x = __fmul_rn(2.0f, cx);
    float c2y = __fmul_rn(2.0f, cy);
    float c2z = __fmul_rn(2.0f, cz);
    for (int s = 0; s < 8; ++s) {
        int j = base + tid + (s << 8);
        float px = pos[j * 3 + 0], py = pos[j * 3 + 1], pz = pos[j * 3 + 2];
        float B = __fadd_rn(__fadd_rn(__fmul_rn(px, px), __fmul_rn(py, py)), __fmul_rn(pz, pz));
        float C = __fmaf_rn(c2z, pz, __fmaf_rn(c2y, py, __fmul_rn(c2x, px)));
        float d2 = __fsub_rn(__fadd_rn(A, B), C);
        bool hit = (d2 <= 0.0625f);
        unsigned long long mk = __ballot(hit);
        int nb = __popcll(mk & ((1ull << ln) - 1ull));
        int tot = __popcll(mk);
        int bidx = 0;
        if (ln == 0 && tot) bidx = atomicAdd(&s_n, tot);
        bidx = __shfl(bidx, 0, 64);
        if (hit) {
            int a = bidx + nb;
            if (a < 1024) { cd2[a] = d2; cidx[a] = j; }
        }
    }
    __syncthreads();
    int V = s_n < 1024 ? s_n : 1024;
    if (V <= KNB) {
        if (tid < KNB) nbr[m * KNB + tid] = (tid < V) ? cidx[tid] : c;
        if (tid == 0) cnt[m] = V;
    } else {
        for (int e = tid; e < V; e += 256) {
            float de = cd2[e]; int ie = cidx[e];
            int rank = 0;
            for (int q = 0; q < V; ++q) {
                float dq = cd2[q];
                rank += (dq < de) || (dq == de && cidx[q] < ie);
            }
            if (rank < KNB) nbr[m * KNB + rank] = cidx[e];
        }
        if (tid == 0) cnt[m] = KNB;
    }
}

// ---------------------------------------------------------------- fused u = x@W1a (blocks 0..255) / v = x[4m]@W1b + b1 (blocks 256..319)
__global__ __launch_bounds__(256) void gemm_xw_kernel(
        const float* __restrict__ x, const u16* __restrict__ W1aT, const u16* __restrict__ W1bT,
        const float* __restrict__ b1, u16* __restrict__ u_out, float* __restrict__ v_out) {
    __shared__ u16 x_lds[64 * 136];
    int blk = blockIdx.x, tid = threadIdx.x;
    int mode = blk >= 256 ? 1 : 0;
    int bb = mode ? blk - 256 : blk;
    const u16* WT = mode ? W1bT : W1aT;
    {
        int r = tid >> 2, q = tid & 3;
        int xrow = bb * 64 + r;
        if (mode) xrow *= 4;
        const float* xp = x + xrow * C_IN + q * 32;
        u16* dst = x_lds + r * 136 + q * 32;
        for (int i = 0; i < 8; ++i) {
            f4v f = *(const f4v*)(xp + i * 4);
            dst[i * 4 + 0] = f2bf(f[0]);
            dst[i * 4 + 1] = f2bf(f[1]);
            dst[i * 4 + 2] = f2bf(f[2]);
            dst[i * 4 + 3] = f2bf(f[3]);
        }
    }
    __syncthreads();
    int lane = tid & 63, w = tid >> 6;
    int quad = lane >> 4, l16 = lane & 15;
    int cb = w * 64;
    f4v acc[4][4] = {};
    for (int k0 = 0; k0 < 128; k0 += 32) {
        s8v a[4], b[4];
        for (int rt = 0; rt < 4; ++rt)
            a[rt] = *(const s8v*)&x_lds[(rt * 16 + l16) * 136 + k0 + quad * 8];
        for (int ct = 0; ct < 4; ++ct)
            b[ct] = *(const s8v*)(WT + (cb + ct * 16 + l16) * 128 + k0 + quad * 8);
        for (int rt = 0; rt < 4; ++rt)
            for (int ct = 0; ct < 4; ++ct)
                acc[rt][ct] = __builtin_amdgcn_mfma_f32_16x16x32_bf16(a[rt], b[ct], acc[rt][ct], 0, 0, 0);
    }
    for (int rt = 0; rt < 4; ++rt)
        for (int ct = 0; ct < 4; ++ct)
            for (int g = 0; g < 4; ++g) {
                int row = rt * 16 + quad * 4 + g;
                int col = cb + ct * 16 + l16;
                float val = acc[rt][ct][g];
                int orow = bb * 64 + row;
                if (mode == 0) u_out[orow * 256 + col] = f2bf(val);
                else           v_out[orow * 256 + col] = val + b1[col];
            }
}

// ---------------------------------------------------------------- fused edge conv
// 512 threads = 8 waves; M-tile 128 (2 centers); 4 pairs/block; grid 512.
// h double-buffered (135 KB LDS), ONE barrier per pair. W2T: 6 of 8 k-slices
// pinned in registers (96 VGPR, loaded once in prologue), last 2 streamed at
// phase-2 top (96-MFMA latency window). Budget: 96 B + 64 acc + 32 streamed
// + ~40 transients ~= 230 < 256 cap of (512,2) -> no spill (r4 lesson).
__global__ __launch_bounds__(512, 2) void edge_kernel(
        const u16* __restrict__ u, const float* __restrict__ v,
        const u16* __restrict__ W2T, const float* __restrict__ W1,
        const float* __restrict__ b2, const float* __restrict__ pos,
        const float* __restrict__ lframes, const int* __restrict__ batch,
        const int* __restrict__ nbrg, const int* __restrict__ cnt,
        float* __restrict__ out0, float* __restrict__ out_pos,
        float* __restrict__ out_batch, float* __restrict__ out_lf) {
    __shared__ u16   h_lds[2][128 * 264];                // 135168 B
    __shared__ float v_lds[2][2][256];
    __shared__ float w1c_lds[768];
    __shared__ f4v   relc_lds[2][2][64];
    __shared__ u16   nbr_lds[2][2][64];

    int blk = blockIdx.x, tid = threadIdx.x;
    int m0 = ((blk & 7) << 9) | ((blk >> 3) << 3);       // 8 consecutive centers, cloud == XCD

    int lane = tid & 63, w = tid >> 6;
    int quad = lane >> 4, l16 = lane & 15;
    int cb = (w & 3) * 64;
    int rbase = (w >> 2) * 64;
    int gsel = w >> 2;

    // ---- B fragments: k-slices 0..5 pinned in registers for the whole kernel
    s8v bfrag[6][4];
    #pragma unroll
    for (int k0 = 0; k0 < 6; ++k0)
        #pragma unroll
        for (int ct = 0; ct < 4; ++ct)
            bfrag[k0][ct] = *(const s8v*)(W2T + (cb + ct * 16 + l16) * 256 + k0 * 32 + quad * 8);

    // ---- prologue
    for (int i = tid; i < 768; i += 512) w1c_lds[i] = W1[65536 + i];
    if (tid < 128) {                                     // meta for pair 0
        int g = tid >> 6, t = tid & 63;
        int mm = m0 + g, cc = mm * 4;
        int j = nbrg[mm * KNB + t];
        nbr_lds[0][g][t] = (u16)j;
        float rx = pos[j * 3 + 0] - pos[cc * 3 + 0];
        float ry = pos[j * 3 + 1] - pos[cc * 3 + 1];
        float rz = pos[j * 3 + 2] - pos[cc * 3 + 2];
        const float* lf = lframes + cc * 9;
        f4v r;
        r[0] = lf[0] * rx + lf[1] * ry + lf[2] * rz;
        r[1] = lf[3] * rx + lf[4] * ry + lf[5] * rz;
        r[2] = lf[6] * rx + lf[7] * ry + lf[8] * rz;
        r[3] = 0.0f;
        relc_lds[0][g][t] = r;
    }
    v_lds[0][tid >> 8][tid & 255] = v[(m0 + (tid >> 8)) * 256 + (tid & 255)];
    if (tid >= 256 && tid < 384) {                       // aux outputs, all 8 centers
        int g = (tid - 256) >> 4, t = tid & 15;
        int mm = m0 + g, cc = mm * 4;
        if (t < 3)            out_pos[mm * 3 + t] = pos[cc * 3 + t];
        else if (t == 3)      out_batch[mm] = (float)batch[cc];
        else if (t < 13)      out_lf[mm * 9 + (t - 4)] = lframes[cc * 9 + (t - 4)];
    }

    int co = (tid & 31) * 8;
    int rs = tid >> 5;                                   // 0..15
    int cv_cur = cnt[m0 + gsel];
    __syncthreads();                                     // meta[0] + w1c ready

    int cv_next = 0;
    for (int p = 0; p < 4; ++p) {
        int pb = p & 1;
        // ---- phase 1: h[pb][128][256] = relu(u[nbr] + v + relc @ W1c)
        #pragma unroll
        for (int g = 0; g < 2; ++g) {
            f4v vq0 = *(const f4v*)&v_lds[pb][g][co];
            f4v vq1 = *(const f4v*)&v_lds[pb][g][co + 4];
            f4v wa0 = *(const f4v*)&w1c_lds[co],       wa1 = *(const f4v*)&w1c_lds[co + 4];
            f4v wb0 = *(const f4v*)&w1c_lds[256 + co], wb1 = *(const f4v*)&w1c_lds[256 + co + 4];
            f4v wc0 = *(const f4v*)&w1c_lds[512 + co], wc1 = *(const f4v*)&w1c_lds[512 + co + 4];
            #pragma unroll
            for (int i2 = 0; i2 < 4; ++i2) {
                int rl = rs + i2 * 16;
                int row = g * 64 + rl;
                int j = (int)nbr_lds[pb][g][rl];
                u4v uu = *(const u4v*)(u + j * 256 + co);
                f4v r = relc_lds[pb][g][rl];
                float p8[8];
                #pragma unroll
                for (int e = 0; e < 8; ++e) {
                    u32 bits = (e & 1) ? (uu[e >> 1] & 0xFFFF0000u) : (uu[e >> 1] << 16);
                    float va = (e < 4) ? vq0[e] : vq1[e - 4];
                    float a0 = (e < 4) ? wa0[e] : wa1[e - 4];
                    float b0 = (e < 4) ? wb0[e] : wb1[e - 4];
                    float c0 = (e < 4) ? wc0[e] : wc1[e - 4];
                    float pre = fmaf(r[0], a0, fmaf(r[1], b0, fmaf(r[2], c0,
                                  va + __uint_as_float(bits))));
                    p8[e] = fmaxf(pre, 0.0f);
                }
                u4v pk;
                #pragma unroll
                for (int d = 0; d < 4; ++d)
                    pk[d] = __builtin_amdgcn_perm(__float_as_uint(p8[2 * d + 1]),
                                                  __float_as_uint(p8[2 * d]), 0x07060302u);
                *(u4v*)&h_lds[pb][row * 264 + co] = pk;
            }
        }
        // ---- prefetch next pair's metadata into the other buffer
        if (p < 3) {
            int nb = pb ^ 1;
            int mbase = m0 + (p + 1) * 2;
            cv_next = cnt[mbase + gsel];
            if (tid < 128) {
                int g = tid >> 6, t = tid & 63;
                int mm = mbase + g, cc = mm * 4;
                int j = nbrg[mm * KNB + t];
                nbr_lds[nb][g][t] = (u16)j;
                float rx = pos[j * 3 + 0] - pos[cc * 3 + 0];
                float ry = pos[j * 3 + 1] - pos[cc * 3 + 1];
                float rz = pos[j * 3 + 2] - pos[cc * 3 + 2];
                const float* lf = lframes + cc * 9;
                f4v r;
                r[0] = lf[0] * rx + lf[1] * ry + lf[2] * rz;
                r[1] = lf[3] * rx + lf[4] * ry + lf[5] * rz;
                r[2] = lf[6] * rx + lf[7] * ry + lf[8] * rz;
                r[3] = 0.0f;
                relc_lds[nb][g][t] = r;
            }
            v_lds[nb][tid >> 8][tid & 255] = v[(mbase + (tid >> 8)) * 256 + (tid & 255)];
        }
        __syncthreads();                                 // h[pb] + meta[nb] ready

        // ---- phase 2: [128x256] @ [256x256]; B from regs (k0<6) + stream (k0=6,7)
        s8v bs[2][4];
        #pragma unroll
        for (int kk = 0; kk < 2; ++kk)
            #pragma unroll
            for (int ct = 0; ct < 4; ++ct)
                bs[kk][ct] = *(const s8v*)(W2T + (cb + ct * 16 + l16) * 256 + (6 + kk) * 32 + quad * 8);
        f4v acc[4][4] = {};
        #pragma unroll
        for (int k0 = 0; k0 < 6; ++k0) {
            s8v a[4];
            #pragma unroll
            for (int rt = 0; rt < 4; ++rt)
                a[rt] = *(const s8v*)&h_lds[pb][(rbase + rt * 16 + l16) * 264 + k0 * 32 + quad * 8];
            #pragma unroll
            for (int rt = 0; rt < 4; ++rt)
                #pragma unroll
                for (int ct = 0; ct < 4; ++ct)
                    acc[rt][ct] = __builtin_amdgcn_mfma_f32_16x16x32_bf16(a[rt], bfrag[k0][ct], acc[rt][ct], 0, 0, 0);
        }
        #pragma unroll
        for (int kk = 0; kk < 2; ++kk) {
            int k0 = 6 + kk;
            s8v a[4];
            #pragma unroll
            for (int rt = 0; rt < 4; ++rt)
                a[rt] = *(const s8v*)&h_lds[pb][(rbase + rt * 16 + l16) * 264 + k0 * 32 + quad * 8];
            #pragma unroll
            for (int rt = 0; rt < 4; ++rt)
                #pragma unroll
                for (int ct = 0; ct < 4; ++ct)
                    acc[rt][ct] = __builtin_amdgcn_mfma_f32_16x16x32_bf16(a[rt], bs[kk][ct], acc[rt][ct], 0, 0, 0);
        }
        // ---- epilogue: masked max over this wave's center, + b2
        int mout = m0 + p * 2 + gsel;
        #pragma unroll
        for (int ct = 0; ct < 4; ++ct) {
            float mx = -__builtin_inff();
            #pragma unroll
            for (int rt = 0; rt < 4; ++rt)
                #pragma unroll
                for (int g = 0; g < 4; ++g) {
                    int row = rt * 16 + quad * 4 + g;
                    float val = acc[rt][ct][g];
                    if (row < cv_cur) mx = fmaxf(mx, val);
                }
            mx = fmaxf(mx, __shfl_xor(mx, 16, 64));
            mx = fmaxf(mx, __shfl_xor(mx, 32, 64));
            if (lane < 16)
                out0[mout * 256 + cb + ct * 16 + l16] = mx + b2[cb + ct * 16 + l16];
        }
        cv_cur = cv_next;
    }
}

extern "C" void kernel_launch(void* const* d_in, const int* in_sizes, int n_in,
                              void* d_out, int out_size, void* d_ws, size_t ws_size,
                              hipStream_t stream) {
    const float* x       = (const float*)d_in[0];
    const float* pos     = (const float*)d_in[1];
    const int*   batch   = (const int*)d_in[2];
    const float* lframes = (const float*)d_in[3];
    const float* W1      = (const float*)d_in[4];
    const float* b1      = (const float*)d_in[5];
    const float* W2      = (const float*)d_in[6];
    const float* b2      = (const float*)d_in[7];

    float* out       = (float*)d_out;
    float* out_pos   = out + M_CTR * 256;
    float* out_batch = out_pos + M_CTR * 3;
    float* out_lf    = out_batch + M_CTR;

    char* ws = (char*)d_ws;
    u16*   u_ws = (u16*)(ws);                    // N*256 bf16   = 8 MB
    float* v_ws = (float*)(ws + 8388608);        // M*256 f32    = 4 MB
    u16*   W1aT = (u16*)(ws + 12582912);
    u16*   W1bT = (u16*)(ws + 12648448);
    u16*   W2T  = (u16*)(ws + 12713984);
    int*   nbr  = (int*)(ws + 12845056);
    int*   cntp = (int*)(ws + 13893632);

    hipLaunchKernelGGL(ballq_kernel, dim3(M_CTR), dim3(256), 0, stream,
                       pos, nbr, cntp, W1, W2, W1aT, W1bT, W2T);
    hipLaunchKernelGGL(gemm_xw_kernel, dim3(320), dim3(256), 0, stream,
                       x, W1aT, W1bT, b1, u_ws, v_ws);
    hipLaunchKernelGGL(edge_kernel, dim3(512), dim3(512), 0, stream,
                       u_ws, v_ws, W2T, W1, b2, pos, lframes, batch, nbr, cntp,
                       out, out_pos, out_batch, out_lf);
}